// Round 6
// baseline (227.233 us; speedup 1.0000x reference)
//
#include <hip/hip_runtime.h>
#include <hip/hip_bf16.h>
#include <cstdint>

// MultiHeadSelfAttention: B=4 S=4096 E=768 H=8 D=96. Inputs/outputs f32.
// Pipeline: weight f32->bf16 prepass -> QKV GEMMs (A: f32 reg-staged with
// fused cvt_pk conversion, W: bf16 global_load_lds; 2-phase double-buffered
// LDS) -> per-token 8x8 head-gram attention -> scrambled reshape ->
// output GEMM + bias (f32 out).

typedef unsigned short u16;
typedef short bf16x8 __attribute__((ext_vector_type(8)));
typedef float f32x4 __attribute__((ext_vector_type(4)));

#define B_  4
#define S_  4096
#define E_  768
#define H_  8
#define D_  96
#define T_  (B_*S_)            // 16384 tokens
#define BM_ 128
#define BN_ 128
#define NT_ (E_/BN_)           // 6 N-tiles

static __device__ __forceinline__ u16 f2bf(float f) {
  unsigned u = __builtin_bit_cast(unsigned, f);
  u += 0x7fffu + ((u >> 16) & 1u);           // round-to-nearest-even
  return (u16)(u >> 16);
}
static __device__ __forceinline__ unsigned pk2(float lo, float hi) {
  return (unsigned)f2bf(lo) | ((unsigned)f2bf(hi) << 16);
}
// HW packed convert (RNE): dst.lo = bf16(lo), dst.hi = bf16(hi)  [T12 recipe]
static __device__ __forceinline__ unsigned cvtpk(float lo, float hi) {
  unsigned r;
  asm("v_cvt_pk_bf16_f32 %0, %1, %2" : "=v"(r) : "v"(lo), "v"(hi));
  return r;
}
static __device__ __forceinline__ float bflo(unsigned u) {
  return __builtin_bit_cast(float, u << 16);
}
static __device__ __forceinline__ float bfhi(unsigned u) {
  return __builtin_bit_cast(float, u & 0xffff0000u);
}

// ---------------- f32 -> bf16 convert, all 4 weight matrices (E*E each)
__global__ __launch_bounds__(256) void conv_w(
    const float* __restrict__ w0, const float* __restrict__ w1,
    const float* __restrict__ w2, const float* __restrict__ w3,
    u16* __restrict__ dst)
{
  const int bpw = (E_ * E_ / 4) / 256;            // 576 blocks per weight
  const int which = blockIdx.x / bpw;
  const float* src = which == 0 ? w0 : which == 1 ? w1 : which == 2 ? w2 : w3;
  const int i = (blockIdx.x - which * bpw) * 256 + threadIdx.x;
  const float4 v = ((const float4*)src)[i];
  uint2 w;
  w.x = pk2(v.x, v.y);
  w.y = pk2(v.z, v.w);
  ((uint2*)(dst + (size_t)which * E_ * E_))[i] = w;
}

// ---------------- GEMM: C[T_,E_] = A[T_,E_] x W[E_,E_](bf16)^T (+bias)
// A: f32 (reg-staged, fused cvt) or bf16 (global_load_lds). 128x128 tile,
// BK=32, 4 waves (2x2, 64x64 wave tile), 16x16x32 MFMA, 2-phase dbuf LDS.
// Granule swizzle: 16B-granule g of row r at slot g ^ ((r>>1)&3).

// B tile (and bf16-A tile) staging via global_load_lds, source pre-swizzled
#define STAGE_OP(BUF, OP, PTR, TBASE, KT)                                      \
  {                                                                            \
    _Pragma("unroll")                                                          \
    for (int c = 0; c < 2; ++c) {                                              \
      const int idx = (c << 8) + tid;                                          \
      const int r = idx >> 2, g = idx & 3;                                     \
      const int gs = g ^ ((r >> 1) & 3);                                       \
      __builtin_amdgcn_global_load_lds(                                        \
          (const __attribute__((address_space(1))) void*)                     \
              ((PTR) + (size_t)((TBASE) + r) * E_ + (KT) + (gs << 3)),         \
          (__attribute__((address_space(3))) void*)                           \
              &lds[BUF][OP][((c << 8) + (wave << 6)) << 3], 16, 0, 0);         \
    }                                                                          \
  }

// f32 A: issue 4x global_load_dwordx4 (early), pack+ds_write later (T14)
#define LOAD_A(KT)                                                             \
  const float4 av0 = *(const float4*)(agp + (KT));                             \
  const float4 av1 = *(const float4*)(agp + (KT) + 4);                         \
  const float4 av2 = *(const float4*)(agp + (KT) + 8);                         \
  const float4 av3 = *(const float4*)(agp + (KT) + 12);

#define WRITE_A(BUF)                                                           \
  {                                                                            \
    uint4 q0, q1;                                                              \
    q0.x = cvtpk(av0.x, av0.y); q0.y = cvtpk(av0.z, av0.w);                    \
    q0.z = cvtpk(av1.x, av1.y); q0.w = cvtpk(av1.z, av1.w);                    \
    q1.x = cvtpk(av2.x, av2.y); q1.y = cvtpk(av2.z, av2.w);                    \
    q1.z = cvtpk(av3.x, av3.y); q1.w = cvtpk(av3.z, av3.w);                    \
    *(uint4*)&lds[BUF][0][ar * 32 + (((ah << 1) ^ aswz) << 3)] = q0;           \
    *(uint4*)&lds[BUF][0][ar * 32 + ((((ah << 1) + 1) ^ aswz) << 3)] = q1;     \
  }

#define LOADFRAGS(BUF)                                                         \
  {                                                                            \
    _Pragma("unroll")                                                          \
    for (int m = 0; m < 4; ++m)                                                \
      a[m] = *(const bf16x8*)&lds[BUF][0][((wr << 6) + (m << 4) + l15) * 32 + slotOff]; \
    _Pragma("unroll")                                                          \
    for (int n = 0; n < 4; ++n)                                                \
      b[n] = *(const bf16x8*)&lds[BUF][1][((wc << 6) + (n << 4) + l15) * 32 + slotOff]; \
  }

#define DOMFMA()                                                               \
  {                                                                            \
    _Pragma("unroll")                                                          \
    for (int m = 0; m < 4; ++m)                                                \
      _Pragma("unroll")                                                        \
      for (int n = 0; n < 4; ++n)                                              \
        acc[m][n] = __builtin_amdgcn_mfma_f32_16x16x32_bf16(a[m], b[n], acc[m][n], 0, 0, 0); \
  }

template<bool A_F32, bool OUT_F32, bool BIAS>
__global__ __launch_bounds__(256, 3) void gemm_nt(
    const void* __restrict__ Av, const u16* __restrict__ Wt,
    const float* __restrict__ bias, void* __restrict__ Cv)
{
  __shared__ u16 lds[2][2][BM_ * 32];            // [buf][A/B][128x32] = 32KB
  const int tid  = threadIdx.x;
  const int wave = tid >> 6;
  const int lane = tid & 63;
  const int wr = wave >> 1, wc = wave & 1;       // 2x2 wave grid, 64x64/wave
  // XCD-chunked swizzle: 768 blocks, 96/XCD -> 16 M-panels x 6 N per XCD
  const int bid = blockIdx.x;
  const int wg  = (bid & 7) * (gridDim.x >> 3) + (bid >> 3);
  const int mT  = wg / NT_;
  const int nT  = wg - mT * NT_;
  const int tM = mT * BM_, tN = nT * BN_;
  const int l15 = lane & 15, l4 = lane >> 4;
  const int slotOff = (l4 ^ ((l15 >> 1) & 3)) << 3;

  const u16*   A16 = (const u16*)Av;
  const float* A32 = (const float*)Av;
  // f32-A staging geometry: thread covers 16 consecutive cols of row ar
  const int ar = tid >> 1, ah = tid & 1;
  const int aswz = (ar >> 1) & 3;
  const float* agp = A32 + (size_t)(tM + ar) * E_ + ah * 16;

  f32x4 acc[4][4] = {};

  // ---- prologue: stage K-tile 0 into buf 0
  if constexpr (A_F32) {
    LOAD_A(0);
    STAGE_OP(0, 1, Wt, tN, 0);
    WRITE_A(0);
  } else {
    STAGE_OP(0, 0, A16, tM, 0);
    STAGE_OP(0, 1, Wt, tN, 0);
  }
  __syncthreads();

  for (int i = 0; i < 12; ++i) {
    const int kt = i << 6;
    {
      bf16x8 a[4], b[4];
      LOADFRAGS(0);
      if constexpr (A_F32) {
        LOAD_A(kt + 32);                  // issue early; MFMA hides latency
        STAGE_OP(1, 1, Wt, tN, kt + 32);
        DOMFMA();
        WRITE_A(1);
      } else {
        STAGE_OP(1, 0, A16, tM, kt + 32);
        STAGE_OP(1, 1, Wt, tN, kt + 32);
        DOMFMA();
      }
    }
    __syncthreads();
    {
      bf16x8 a[4], b[4];
      LOADFRAGS(1);
      if (i < 11) {
        if constexpr (A_F32) {
          LOAD_A(kt + 64);
          STAGE_OP(0, 1, Wt, tN, kt + 64);
          DOMFMA();
          WRITE_A(0);
        } else {
          STAGE_OP(0, 0, A16, tM, kt + 64);
          STAGE_OP(0, 1, Wt, tN, kt + 64);
          DOMFMA();
        }
      } else {
        DOMFMA();
      }
    }
    __syncthreads();
  }

  // epilogue: C/D layout col=lane&15, row=(lane>>4)*4+reg  [m89/m91]
  if constexpr (OUT_F32) {
    // f32 direct stores: 16 lanes x 4B contiguous -> full 64B lines
#pragma unroll
    for (int m = 0; m < 4; ++m) {
#pragma unroll
      for (int n = 0; n < 4; ++n) {
        const int row = tM + (wr << 6) + (m << 4) + (l4 << 2);
        const int col = tN + (wc << 6) + (n << 4) + l15;
        const float badd = BIAS ? bias[col] : 0.f;
#pragma unroll
        for (int r = 0; r < 4; ++r)
          ((float*)Cv)[(size_t)(row + r) * E_ + col] = acc[m][n][r] + badd;
      }
    }
  } else {
    // bf16: stage C tile (128x128 u16 = 32KB) in LDS, write back coalesced
    __syncthreads();
    u16* lC = (u16*)lds;
#pragma unroll
    for (int m = 0; m < 4; ++m)
#pragma unroll
      for (int n = 0; n < 4; ++n) {
        const int row = (wr << 6) + (m << 4) + (l4 << 2);
        const int col = (wc << 6) + (n << 4) + l15;
#pragma unroll
        for (int r = 0; r < 4; ++r)
          lC[(row + r) * BN_ + col] = f2bf(acc[m][n][r]);
      }
    __syncthreads();
#pragma unroll
    for (int p = 0; p < 8; ++p) {
      const int row = (p << 4) + (wave << 2) + l4;   // 16 rows per pass
      const bf16x8 v = *(const bf16x8*)&lC[row * BN_ + (l15 << 3)];
      *(bf16x8*)((u16*)Cv + (size_t)(tM + row) * E_ + tN + (l15 << 3)) = v;
    }
  }
}

// ---------------- per-token attention: 1 wave per token
// att[i,j] = sum_d Q[t,i*96+d]*K[t,j*96+d]; masked softmax over j;
// out2D[b, 512*i + s/8, 96*(s%8)+d] = sum_j p[i,j]*V[t, j*96+d]
__global__ __launch_bounds__(256) void attn_tok(
    const u16* __restrict__ Q, const u16* __restrict__ K,
    const u16* __restrict__ V, const int* __restrict__ mask,
    u16* __restrict__ O)
{
  __shared__ float pl[4][8][8];
  const int tid = threadIdx.x, wave = tid >> 6, lane = tid & 63;
  const int t = blockIdx.x * 4 + wave;
  const int s = t & (S_ - 1);
  const int b = t >> 12;
  const int i = lane >> 3, j = lane & 7;

  const uint4* qp = (const uint4*)(Q + (size_t)t * E_ + i * D_);
  const uint4* kp = (const uint4*)(K + (size_t)t * E_ + j * D_);
  float acc = 0.f;
#pragma unroll
  for (int it = 0; it < 12; ++it) {   // 96 bf16 = 12 x uint4
    const uint4 qv = qp[it], kv = kp[it];
    acc += bflo(qv.x) * bflo(kv.x) + bfhi(qv.x) * bfhi(kv.x);
    acc += bflo(qv.y) * bflo(kv.y) + bfhi(qv.y) * bfhi(kv.y);
    acc += bflo(qv.z) * bflo(kv.z) + bfhi(qv.z) * bfhi(kv.z);
    acc += bflo(qv.w) * bflo(kv.w) + bfhi(qv.w) * bfhi(kv.w);
  }
  // mask==0 -> -1e20 everywhere -> softmax degenerates to 1/8
  float sv = (mask[t] == 0) ? -1e20f : acc;
  sv *= 0.03608439182435161f;          // 1/sqrt(768)
  float mx = sv;
  mx = fmaxf(mx, __shfl_xor(mx, 1));
  mx = fmaxf(mx, __shfl_xor(mx, 2));
  mx = fmaxf(mx, __shfl_xor(mx, 4));
  const float e = __expf(sv - mx);
  float sm = e;
  sm += __shfl_xor(sm, 1);
  sm += __shfl_xor(sm, 2);
  sm += __shfl_xor(sm, 4);
  pl[wave][i][j] = e / sm;
  __syncthreads();

  // PV: lane (i2, db) owns d = db*12 .. db*12+11 of head i2
  const int i2 = lane >> 3, db = lane & 7;
  float o[12] = {};
#pragma unroll
  for (int jj = 0; jj < 8; ++jj) {
    const float pj = pl[wave][i2][jj];
    const uint2* vp = (const uint2*)(V + (size_t)t * E_ + jj * D_ + db * 12);
    const uint2 v0 = vp[0], v1 = vp[1], v2 = vp[2];
    o[0]  += pj * bflo(v0.x);  o[1]  += pj * bfhi(v0.x);
    o[2]  += pj * bflo(v0.y);  o[3]  += pj * bfhi(v0.y);
    o[4]  += pj * bflo(v1.x);  o[5]  += pj * bfhi(v1.x);
    o[6]  += pj * bflo(v1.y);  o[7]  += pj * bfhi(v1.y);
    o[8]  += pj * bflo(v2.x);  o[9]  += pj * bfhi(v2.x);
    o[10] += pj * bflo(v2.y);  o[11] += pj * bfhi(v2.y);
  }
  // scrambled reshape [b,h,s,d] -> [b, 512h + s/8, 96(s%8)+d]
  const size_t row = (size_t)b * S_ + 512 * i2 + (s >> 3);
  u16* op = O + row * E_ + 96 * (s & 7) + db * 12;
  uint2 w0, w1, w2;
  w0.x = pk2(o[0], o[1]);
  w0.y = pk2(o[2], o[3]);
  w1.x = pk2(o[4], o[5]);
  w1.y = pk2(o[6], o[7]);
  w2.x = pk2(o[8], o[9]);
  w2.y = pk2(o[10], o[11]);
  ((uint2*)op)[0] = w0;
  ((uint2*)op)[1] = w1;
  ((uint2*)op)[2] = w2;
}

extern "C" void kernel_launch(void* const* d_in, const int* in_sizes, int n_in,
                              void* d_out, int out_size, void* d_ws, size_t ws_size,
                              hipStream_t stream)
{
  const float* values = (const float*)d_in[0];
  const float* keys   = (const float*)d_in[1];
  const float* query  = (const float*)d_in[2];
  const int*   mask   = (const int*)d_in[3];
  const float* Wv = (const float*)d_in[4];
  const float* Wk = (const float*)d_in[5];
  const float* Wq = (const float*)d_in[6];
  const float* Wo = (const float*)d_in[7];
  const float* bo = (const float*)d_in[8];

  const size_t TE = (size_t)T_ * E_;
  const size_t EE = (size_t)E_ * E_;
  u16* Qb = (u16*)d_ws;          // 25.2 MB each (bf16)
  u16* Kb = Qb + TE;
  u16* Vb = Kb + TE;
  u16* O2 = Vb + TE;             // attention output (scrambled layout)
  u16* Wb = O2 + TE;             // 4 x 1.18 MB bf16 weights (105.4 MB total)

  dim3 blk(256);
  dim3 gg(T_ / BM_ * NT_);       // 768 blocks = 3/CU, one cohort

  conv_w<<<dim3(4 * (E_ * E_ / 4) / 256), blk, 0, stream>>>(Wq, Wk, Wv, Wo, Wb);

  gemm_nt<true, false, false><<<gg, blk, 0, stream>>>(query,  Wb + 0 * EE, nullptr, Qb);
  gemm_nt<true, false, false><<<gg, blk, 0, stream>>>(keys,   Wb + 1 * EE, nullptr, Kb);
  gemm_nt<true, false, false><<<gg, blk, 0, stream>>>(values, Wb + 2 * EE, nullptr, Vb);

  attn_tok<<<dim3(T_ / 4), blk, 0, stream>>>(Qb, Kb, Vb, mask, O2);

  gemm_nt<false, true, true><<<gg, blk, 0, stream>>>(O2, Wb + 3 * EE, bo, (float*)d_out);
}

// Round 7
// 184.741 us; speedup vs baseline: 1.2300x; 1.2300x over previous
//
#include <hip/hip_runtime.h>
#include <hip/hip_bf16.h>
#include <cstdint>

// MultiHeadSelfAttention: B=4 S=4096 E=768 H=8 D=96. Inputs/outputs f32.
// Pipeline: f32->bf16 prepass (activations + weights) -> GEMMs with
// 256x192 tile, 8 waves, BK=64 double-buffered LDS, 4 phases/K-tile,
// raw s_barrier + counted vmcnt (drain only at iter boundary), setprio
// around MFMA -> per-token 8x8 head-gram attention -> scrambled reshape
// -> output GEMM + bias (f32 out).

typedef unsigned short u16;
typedef short bf16x8 __attribute__((ext_vector_type(8)));
typedef float f32x4 __attribute__((ext_vector_type(4)));

#define B_  4
#define S_  4096
#define E_  768
#define H_  8
#define D_  96
#define T_  (B_*S_)            // 16384 tokens
#define BM_ 256
#define BN_ 192

static __device__ __forceinline__ u16 f2bf(float f) {
  unsigned u = __builtin_bit_cast(unsigned, f);
  u += 0x7fffu + ((u >> 16) & 1u);           // round-to-nearest-even
  return (u16)(u >> 16);
}
static __device__ __forceinline__ unsigned pk2(float lo, float hi) {
  return (unsigned)f2bf(lo) | ((unsigned)f2bf(hi) << 16);
}
static __device__ __forceinline__ float bflo(unsigned u) {
  return __builtin_bit_cast(float, u << 16);
}
static __device__ __forceinline__ float bfhi(unsigned u) {
  return __builtin_bit_cast(float, u & 0xffff0000u);
}

// ---------------- f32 -> bf16 convert (activations), one tensor per launch
__global__ __launch_bounds__(256) void conv_bf16(
    const float* __restrict__ src, u16* __restrict__ dst)
{
  const int i = blockIdx.x * 256 + threadIdx.x;   // float4 index
  const float4 v = ((const float4*)src)[i];
  uint2 w;
  w.x = pk2(v.x, v.y);
  w.y = pk2(v.z, v.w);
  ((uint2*)dst)[i] = w;
}

// ---------------- f32 -> bf16 convert, all 4 weight matrices (E*E each)
__global__ __launch_bounds__(256) void conv_w(
    const float* __restrict__ w0, const float* __restrict__ w1,
    const float* __restrict__ w2, const float* __restrict__ w3,
    u16* __restrict__ dst)
{
  const int bpw = (E_ * E_ / 4) / 256;            // 576 blocks per weight
  const int which = blockIdx.x / bpw;
  const float* src = which == 0 ? w0 : which == 1 ? w1 : which == 2 ? w2 : w3;
  const int i = (blockIdx.x - which * bpw) * 256 + threadIdx.x;
  const float4 v = ((const float4*)src)[i];
  uint2 w;
  w.x = pk2(v.x, v.y);
  w.y = pk2(v.z, v.w);
  ((uint2*)(dst + (size_t)which * E_ * E_))[i] = w;
}

// ---------------- GEMM: C[T_,E_] = A[T_,E_](bf16) x W[E_,E_](bf16)^T (+bias)
// 256x192 tile, BK=64, 512 thr (8 waves, 2M x 4N; wave tile 128x48).
// LDS: A 256x64 (32KB) + B 192x64 (24KB), double-buffered = 112KB.
// Swizzle: 16B-granule g of row r stored at slot g ^ (r&7) -> conflict-free.
// Schedule per K-tile t (4 phases): {ds_read frags | issue gload_lds for
// t+1 -> s_barrier -> setprio(1) 12 MFMA setprio(0) -> s_barrier}; single
// per-wave vmcnt(0) at iter boundary (loads keep flying across barriers).

#define GLOAD(SRC, DST)                                                        \
  __builtin_amdgcn_global_load_lds(                                            \
      (const __attribute__((address_space(1))) void*)(SRC),                    \
      (__attribute__((address_space(3))) void*)(DST), 16, 0, 0)

#define SA(BUF, I, KT) GLOAD(sA[I] + (KT), &lA[BUF][(((I) << 3) + wave) * 512])
#define SB(BUF, I, KT) GLOAD(sB[I] + (KT), &lB[BUF][(((I) << 3) + wave) * 512])

// A frag: row = wr*128 + MH*64 + M*16 + l15, granule = (KK*4+l4) ^ (row&7)
#define RDA(BUF, MH, KK, M)                                                    \
  (*(const bf16x8*)&lA[BUF][((wr << 7) + ((MH) << 6) + ((M) << 4) + l15) * 64 +\
      (((((KK) << 2) + l4) ^ (((MH) << 6) + ((M) << 4) + l15 ? ((((MH) << 6) + ((M) << 4) + l15) & 7) : 0)) << 3)])

#define MFMA12(MB)                                                             \
  {                                                                            \
    _Pragma("unroll")                                                          \
    for (int m_ = 0; m_ < 4; ++m_) {                                           \
      acc[(MB) + m_][0] = __builtin_amdgcn_mfma_f32_16x16x32_bf16(a[m_], b[0], acc[(MB) + m_][0], 0, 0, 0); \
      acc[(MB) + m_][1] = __builtin_amdgcn_mfma_f32_16x16x32_bf16(a[m_], b[1], acc[(MB) + m_][1], 0, 0, 0); \
      acc[(MB) + m_][2] = __builtin_amdgcn_mfma_f32_16x16x32_bf16(a[m_], b[2], acc[(MB) + m_][2], 0, 0, 0); \
    }                                                                          \
  }

template<bool OUT_F32, bool BIAS>
__global__ __launch_bounds__(512, 2) void gemm_big(
    const u16* __restrict__ A, const u16* __restrict__ Wt,
    const float* __restrict__ bias, void* __restrict__ Cv)
{
  __shared__ u16 lA[2][256 * 64];                 // 64 KB
  __shared__ u16 lB[2][192 * 64];                 // 48 KB
  const int tid = threadIdx.x, wave = tid >> 6, lane = tid & 63;
  const int wr = wave >> 2, wcn = wave & 3;       // 2M x 4N wave grid
  // XCD-chunked swizzle (256 blocks, 32/XCD = 8 M-panels x 4 N)
  const int wg = ((blockIdx.x & 7) << 5) + (blockIdx.x >> 3);
  const int tM = (wg >> 2) << 8, tN = (wg & 3) * BN_;
  const int l15 = lane & 15, l4 = lane >> 4;
  // staging geometry: chunk = i*8+wave covers rows chunk*8..+8 (1KB each)
  const int srow = lane >> 3;
  const int sg   = (lane & 7) ^ srow;             // source granule pre-swizzle

  const u16* sA[4];
  const u16* sB[3];
#pragma unroll
  for (int i = 0; i < 4; ++i)
    sA[i] = A + (size_t)(tM + (((i << 3) + wave) << 3) + srow) * E_ + (sg << 3);
#pragma unroll
  for (int i = 0; i < 3; ++i)
    sB[i] = Wt + (size_t)(tN + (((i << 3) + wave) << 3) + srow) * E_ + (sg << 3);

  f32x4 acc[8][3] = {};

  // prologue: stage K-tile 0 into buf 0, drain, barrier
#pragma unroll
  for (int i = 0; i < 4; ++i) SA(0, i, 0);
#pragma unroll
  for (int i = 0; i < 3; ++i) SB(0, i, 0);
  asm volatile("s_waitcnt vmcnt(0)" ::: "memory");
  __builtin_amdgcn_s_barrier();

  for (int t = 0; t < 12; ++t) {
    const int cur = t & 1, nxt = cur ^ 1;
    const int ktn = (t + 1) << 6;
    const bool pf = (t < 11);
    bf16x8 a[4], b[3];

    // -------- phase 0: kk=0, mh=0; read B(kk0); stage A0,A1,A2(t+1)
#pragma unroll
    for (int m = 0; m < 4; ++m) {
      const int row = (wr << 7) + (m << 4) + l15;
      a[m] = *(const bf16x8*)&lA[cur][row * 64 + ((l4 ^ (row & 7)) << 3)];
    }
#pragma unroll
    for (int n = 0; n < 3; ++n) {
      const int row = wcn * 48 + (n << 4) + l15;
      b[n] = *(const bf16x8*)&lB[cur][row * 64 + ((l4 ^ (row & 7)) << 3)];
    }
    if (pf) { SA(nxt, 0, ktn); SA(nxt, 1, ktn); SA(nxt, 2, ktn); }
    __builtin_amdgcn_s_barrier();
    __builtin_amdgcn_s_setprio(1);
    MFMA12(0);
    __builtin_amdgcn_s_setprio(0);
    __builtin_amdgcn_s_barrier();

    // -------- phase 1: kk=0, mh=1; reuse b; stage A3,B0
#pragma unroll
    for (int m = 0; m < 4; ++m) {
      const int row = (wr << 7) + 64 + (m << 4) + l15;
      a[m] = *(const bf16x8*)&lA[cur][row * 64 + ((l4 ^ (row & 7)) << 3)];
    }
    if (pf) { SA(nxt, 3, ktn); SB(nxt, 0, ktn); }
    __builtin_amdgcn_s_barrier();
    __builtin_amdgcn_s_setprio(1);
    MFMA12(4);
    __builtin_amdgcn_s_setprio(0);
    __builtin_amdgcn_s_barrier();

    // -------- phase 2: kk=1, mh=0; read B(kk1); stage B1,B2
#pragma unroll
    for (int m = 0; m < 4; ++m) {
      const int row = (wr << 7) + (m << 4) + l15;
      a[m] = *(const bf16x8*)&lA[cur][row * 64 + (((4 + l4) ^ (row & 7)) << 3)];
    }
#pragma unroll
    for (int n = 0; n < 3; ++n) {
      const int row = wcn * 48 + (n << 4) + l15;
      b[n] = *(const bf16x8*)&lB[cur][row * 64 + (((4 + l4) ^ (row & 7)) << 3)];
    }
    if (pf) { SB(nxt, 1, ktn); SB(nxt, 2, ktn); }
    __builtin_amdgcn_s_barrier();
    __builtin_amdgcn_s_setprio(1);
    MFMA12(0);
    __builtin_amdgcn_s_setprio(0);
    __builtin_amdgcn_s_barrier();

    // -------- phase 3: kk=1, mh=1; reuse b; no stage
#pragma unroll
    for (int m = 0; m < 4; ++m) {
      const int row = (wr << 7) + 64 + (m << 4) + l15;
      a[m] = *(const bf16x8*)&lA[cur][row * 64 + (((4 + l4) ^ (row & 7)) << 3)];
    }
    __builtin_amdgcn_s_barrier();
    __builtin_amdgcn_s_setprio(1);
    MFMA12(4);
    __builtin_amdgcn_s_setprio(0);
    // iter boundary: own prefetch loads must be done, then block-wide sync
    if (pf) asm volatile("s_waitcnt vmcnt(0)" ::: "memory");
    __builtin_amdgcn_s_barrier();
  }

  // epilogue: C/D layout col=lane&15, row=(lane>>4)*4+reg  [m89/m91]
  const int cr = l4 << 2;
#pragma unroll
  for (int m = 0; m < 8; ++m) {
#pragma unroll
    for (int n = 0; n < 3; ++n) {
      const int row = tM + (wr << 7) + (m << 4) + cr;
      const int col = tN + wcn * 48 + (n << 4) + l15;
      const float badd = BIAS ? bias[col] : 0.f;
#pragma unroll
      for (int r = 0; r < 4; ++r) {
        const float val = acc[m][n][r] + badd;
        if constexpr (OUT_F32)
          ((float*)Cv)[(size_t)(row + r) * E_ + col] = val;
        else
          ((u16*)Cv)[(size_t)(row + r) * E_ + col] = f2bf(val);
      }
    }
  }
}

// ---------------- per-token attention: 1 wave per token
// att[i,j] = sum_d Q[t,i*96+d]*K[t,j*96+d]; masked softmax over j;
// out2D[b, 512*i + s/8, 96*(s%8)+d] = sum_j p[i,j]*V[t, j*96+d]
__global__ __launch_bounds__(256) void attn_tok(
    const u16* __restrict__ Q, const u16* __restrict__ K,
    const u16* __restrict__ V, const int* __restrict__ mask,
    u16* __restrict__ O)
{
  __shared__ float pl[4][8][8];
  const int tid = threadIdx.x, wave = tid >> 6, lane = tid & 63;
  const int t = blockIdx.x * 4 + wave;
  const int s = t & (S_ - 1);
  const int b = t >> 12;
  const int i = lane >> 3, j = lane & 7;

  const uint4* qp = (const uint4*)(Q + (size_t)t * E_ + i * D_);
  const uint4* kp = (const uint4*)(K + (size_t)t * E_ + j * D_);
  float acc = 0.f;
#pragma unroll
  for (int it = 0; it < 12; ++it) {   // 96 bf16 = 12 x uint4
    const uint4 qv = qp[it], kv = kp[it];
    acc += bflo(qv.x) * bflo(kv.x) + bfhi(qv.x) * bfhi(kv.x);
    acc += bflo(qv.y) * bflo(kv.y) + bfhi(qv.y) * bfhi(kv.y);
    acc += bflo(qv.z) * bflo(kv.z) + bfhi(qv.z) * bfhi(kv.z);
    acc += bflo(qv.w) * bflo(kv.w) + bfhi(qv.w) * bfhi(kv.w);
  }
  // mask==0 -> -1e20 everywhere -> softmax degenerates to 1/8
  float sv = (mask[t] == 0) ? -1e20f : acc;
  sv *= 0.03608439182435161f;          // 1/sqrt(768)
  float mx = sv;
  mx = fmaxf(mx, __shfl_xor(mx, 1));
  mx = fmaxf(mx, __shfl_xor(mx, 2));
  mx = fmaxf(mx, __shfl_xor(mx, 4));
  const float e = __expf(sv - mx);
  float sm = e;
  sm += __shfl_xor(sm, 1);
  sm += __shfl_xor(sm, 2);
  sm += __shfl_xor(sm, 4);
  pl[wave][i][j] = e / sm;
  __syncthreads();

  // PV: lane (i2, db) owns d = db*12 .. db*12+11 of head i2
  const int i2 = lane >> 3, db = lane & 7;
  float o[12] = {};
#pragma unroll
  for (int jj = 0; jj < 8; ++jj) {
    const float pj = pl[wave][i2][jj];
    const uint2* vp = (const uint2*)(V + (size_t)t * E_ + jj * D_ + db * 12);
    const uint2 v0 = vp[0], v1 = vp[1], v2 = vp[2];
    o[0]  += pj * bflo(v0.x);  o[1]  += pj * bfhi(v0.x);
    o[2]  += pj * bflo(v0.y);  o[3]  += pj * bfhi(v0.y);
    o[4]  += pj * bflo(v1.x);  o[5]  += pj * bfhi(v1.x);
    o[6]  += pj * bflo(v1.y);  o[7]  += pj * bfhi(v1.y);
    o[8]  += pj * bflo(v2.x);  o[9]  += pj * bfhi(v2.x);
    o[10] += pj * bflo(v2.y);  o[11] += pj * bfhi(v2.y);
  }
  // scrambled reshape [b,h,s,d] -> [b, 512h + s/8, 96(s%8)+d]
  const size_t row = (size_t)b * S_ + 512 * i2 + (s >> 3);
  u16* op = O + row * E_ + 96 * (s & 7) + db * 12;
  uint2 w0, w1, w2;
  w0.x = pk2(o[0], o[1]);
  w0.y = pk2(o[2], o[3]);
  w1.x = pk2(o[4], o[5]);
  w1.y = pk2(o[6], o[7]);
  w2.x = pk2(o[8], o[9]);
  w2.y = pk2(o[10], o[11]);
  ((uint2*)op)[0] = w0;
  ((uint2*)op)[1] = w1;
  ((uint2*)op)[2] = w2;
}

extern "C" void kernel_launch(void* const* d_in, const int* in_sizes, int n_in,
                              void* d_out, int out_size, void* d_ws, size_t ws_size,
                              hipStream_t stream)
{
  const float* values = (const float*)d_in[0];
  const float* keys   = (const float*)d_in[1];
  const float* query  = (const float*)d_in[2];
  const int*   mask   = (const int*)d_in[3];
  const float* Wv = (const float*)d_in[4];
  const float* Wk = (const float*)d_in[5];
  const float* Wq = (const float*)d_in[6];
  const float* Wo = (const float*)d_in[7];
  const float* bo = (const float*)d_in[8];

  const size_t TE = (size_t)T_ * E_;
  const size_t EE = (size_t)E_ * E_;
  u16* Qb = (u16*)d_ws;          // 25.2 MB each (bf16)
  u16* Kb = Qb + TE;
  u16* Vb = Kb + TE;
  u16* Xt = Vb + TE;             // A-convert scratch; later aliased as O2
  u16* Wb = Xt + TE;             // 4 x 1.18 MB bf16 weights (105.4 MB total)

  dim3 gg(T_ / BM_ * (E_ / BN_));   // 64 x 4 = 256 blocks = 1/CU
  dim3 gc(TE / 4 / 256);            // 12288 blocks

  conv_w<<<dim3(4 * (E_ * E_ / 4) / 256), dim3(256), 0, stream>>>(Wq, Wk, Wv, Wo, Wb);

  conv_bf16<<<gc, dim3(256), 0, stream>>>(query, Xt);
  gemm_big<false, false><<<gg, dim3(512), 0, stream>>>(Xt, Wb + 0 * EE, nullptr, Qb);
  conv_bf16<<<gc, dim3(256), 0, stream>>>(keys, Xt);
  gemm_big<false, false><<<gg, dim3(512), 0, stream>>>(Xt, Wb + 1 * EE, nullptr, Kb);
  conv_bf16<<<gc, dim3(256), 0, stream>>>(values, Xt);
  gemm_big<false, false><<<gg, dim3(512), 0, stream>>>(Xt, Wb + 2 * EE, nullptr, Vb);

  attn_tok<<<dim3(T_ / 4), dim3(256), 0, stream>>>(Qb, Kb, Vb, mask, Xt /*O2*/);

  gemm_big<true, true><<<gg, dim3(512), 0, stream>>>(Xt /*O2*/, Wb + 3 * EE, bo, (float*)d_out);
}